// Round 16
// baseline (621.332 us; speedup 1.0000x reference)
//
#include <hip/hip_runtime.h>
#include <stdint.h>

#define BB 4
#define SS 2048
#define HID 1024
#define NH 16
#define DH 64

using bf16x8 = __attribute__((ext_vector_type(8))) short;
using f32x4  = __attribute__((ext_vector_type(4))) float;

#define LOG2E 1.44269504088896340736f

__device__ __forceinline__ ushort f2bf(float f) {
  union { float f; uint32_t u; } v; v.f = f;
  return (ushort)((v.u + 0x7FFFu + ((v.u >> 16) & 1u)) >> 16);
}

__device__ __forceinline__ uint32_t cvt_pk_bf16(float a, float b) {
  uint32_t r;
  asm("v_cvt_pk_bf16_f32 %0, %1, %2" : "=v"(r) : "v"(a), "v"(b));
  return r;
}

__device__ __forceinline__ float exp2_hw(float x) {
  float r;
  asm("v_exp_f32 %0, %1" : "=v"(r) : "v"(x));
  return r;
}

__device__ __forceinline__ void gload_lds16(const ushort* g, ushort* l) {
  __builtin_amdgcn_global_load_lds(
      (const __attribute__((address_space(1))) uint32_t*)g,
      (__attribute__((address_space(3))) uint32_t*)l, 16, 0, 0);
}

// V-column permutation within each 64-key block (see attn P-packing):
// kk = [j5, j3, j2, j4, j1, j0]
__device__ __forceinline__ int vperm(int j) {
  return (j & 0x23) | ((j & 0x0C) << 1) | ((j & 0x10) >> 2);
}

// ---------------- kernel 1: f32 -> bf16 convert (X, W concat) + mask*log2e ---
__global__ void cvt_kernel(const float* __restrict__ x, const float* __restrict__ wq,
                           const float* __restrict__ wk, const float* __restrict__ wv,
                           const float* __restrict__ am,
                           ushort* __restrict__ xbf, ushort* __restrict__ wbf,
                           float* __restrict__ maskL) {
  const int64_t NX4 = (int64_t)BB * SS * HID / 4;   // 2097152
  const int64_t NW4 = (int64_t)HID * HID / 4;       // 262144 = 2^18
  const int64_t NWT = 3 * NW4;                      // 786432
  int64_t i = (int64_t)blockIdx.x * blockDim.x + threadIdx.x;
  if (i >= NX4 + NWT) {
    const int64_t jm = i - (NX4 + NWT);
    float4 v = ((const float4*)am)[jm];
    v.x *= LOG2E; v.y *= LOG2E; v.z *= LOG2E; v.w *= LOG2E;
    ((float4*)maskL)[jm] = v;
    return;
  }
  float4 v;
  ushort4* dst;
  if (i < NX4) {
    v = ((const float4*)x)[i];
    dst = (ushort4*)xbf + i;
  } else {
    int64_t j = i - NX4;
    int w = (int)(j >> 18);
    int64_t k = j & (NW4 - 1);
    const float* src = (w == 0) ? wq : (w == 1) ? wk : wv;
    v = ((const float4*)src)[k];
    dst = (ushort4*)wbf + j;
  }
  ushort4 o;
  o.x = f2bf(v.x); o.y = f2bf(v.y); o.z = f2bf(v.z); o.w = f2bf(v.w);
  *dst = o;
}

// ---------------- kernel 2: QKV projection GEMM (256x192, BK=64, 4-phase) ----
__global__ __launch_bounds__(512, 2) void qkv_gemm(
    const ushort* __restrict__ xbf, const ushort* __restrict__ wbf,
    const float* __restrict__ bq, const float* __restrict__ bk,
    const float* __restrict__ bv,
    ushort* __restrict__ qws, ushort* __restrict__ kws, ushort* __restrict__ vtws) {
  __shared__ __align__(16) char LDSX[114688];   // A: 64KB dbuf, B: 48KB dbuf

  const int tid = threadIdx.x, wid = tid >> 6, lane = tid & 63;
  const int colL = lane & 15, rowg = lane >> 4;
  const int wr = wid >> 2, wc = wid & 3;

  const int wgid = (blockIdx.x & 7) * 64 + (blockIdx.x >> 3);
  const int m0 = (wgid >> 4) * 256;
  const int n0 = (wgid & 15) * 192;

  const int swzcol = (((tid & 7) * 16) ^ (((tid >> 3) & 7) << 4)) >> 1;
  const ushort* aSrc = xbf + (int64_t)(m0 + (tid >> 3)) * HID + swzcol;
  const ushort* bSrc = wbf + (int64_t)(n0 + (tid >> 3)) * HID + swzcol;
  ushort* Al_u = (ushort*)LDSX;
  ushort* Bl_u = (ushort*)(LDSX + 65536);

  auto stageA = [&](int kt, int r, int ps) {
    gload_lds16(aSrc + r * 64 * HID + kt * 64, Al_u + ps * 16384 + r * 4096 + wid * 512);
  };
  auto stageB = [&](int kt, int r, int ps) {
    gload_lds16(bSrc + r * 64 * HID + kt * 64, Bl_u + ps * 12288 + r * 4096 + wid * 512);
  };

  const int xsw = (colL & 7) << 4;
  const int offk0 = (rowg * 16) ^ xsw;
  const int offk1 = (64 + rowg * 16) ^ xsw;
  const int arow = (wr * 128 + colL) * 128;
  const int brow = (wc * 48 + colL) * 128;
  const char* AlC = (const char*)LDSX;
  const char* BlC = (const char*)(LDSX + 65536);

  f32x4 acc[8][3];
#pragma unroll
  for (int i = 0; i < 8; ++i)
#pragma unroll
    for (int j = 0; j < 3; ++j)
#pragma unroll
      for (int r = 0; r < 4; ++r) acc[i][j][r] = 0.f;

  stageB(0, 0, 0); stageB(0, 1, 0); stageB(0, 2, 0);
  stageA(0, 0, 0); stageA(0, 2, 0); stageA(0, 1, 0); stageA(0, 3, 0);
  asm volatile("s_waitcnt vmcnt(2)" ::: "memory");
  __builtin_amdgcn_s_barrier();

#define DO_PHASE(P, S1, S2, PRE_BAR2)                                          \
  {                                                                            \
    const int mfa = 2 * (P), mfb = 2 * (P) + 1;                                \
    bf16x8 aA0 = *(const bf16x8*)(kA0 + mfa * 2048);                           \
    bf16x8 aA1 = *(const bf16x8*)(kA1 + mfa * 2048);                           \
    bf16x8 aB0 = *(const bf16x8*)(kA0 + mfb * 2048);                           \
    bf16x8 aB1 = *(const bf16x8*)(kA1 + mfb * 2048);                           \
    S1; S2;                                                                    \
    __builtin_amdgcn_s_setprio(1);                                             \
    _Pragma("unroll")                                                          \
    for (int nf = 0; nf < 3; ++nf) {                                           \
      acc[mfa][nf] = __builtin_amdgcn_mfma_f32_16x16x32_bf16(aA0, bfr[nf][0], acc[mfa][nf], 0, 0, 0); \
      acc[mfa][nf] = __builtin_amdgcn_mfma_f32_16x16x32_bf16(aA1, bfr[nf][1], acc[mfa][nf], 0, 0, 0); \
      acc[mfb][nf] = __builtin_amdgcn_mfma_f32_16x16x32_bf16(aB0, bfr[nf][0], acc[mfb][nf], 0, 0, 0); \
      acc[mfb][nf] = __builtin_amdgcn_mfma_f32_16x16x32_bf16(aB1, bfr[nf][1], acc[mfb][nf], 0, 0, 0); \
    }                                                                          \
    __builtin_amdgcn_s_setprio(0);                                             \
    PRE_BAR2;                                                                  \
    __builtin_amdgcn_s_barrier();                                              \
  }

  for (int t = 0; t < 16; ++t) {
    const int p = t & 1;
    const int ps = p ^ 1;
    const bool st = (t < 15);
    const int kt = t + 1;
    const char* kA0 = AlC + p * 32768 + arow + offk0;
    const char* kA1 = AlC + p * 32768 + arow + offk1;
    const char* kB0 = BlC + p * 24576 + brow + offk0;
    const char* kB1 = BlC + p * 24576 + brow + offk1;

    bf16x8 bfr[3][2];
#pragma unroll
    for (int nf = 0; nf < 3; ++nf) {
      bfr[nf][0] = *(const bf16x8*)(kB0 + nf * 2048);
      bfr[nf][1] = *(const bf16x8*)(kB1 + nf * 2048);
    }

    DO_PHASE(0, if (st) stageB(kt, 0, ps), if (st) stageB(kt, 1, ps), )
    DO_PHASE(1, if (st) stageB(kt, 2, ps), if (st) stageA(kt, 0, ps),
             if (t == 15) { asm volatile("s_waitcnt vmcnt(0)" ::: "memory"); }
             else        { asm volatile("s_waitcnt vmcnt(4)" ::: "memory"); })
    DO_PHASE(2, if (st) stageA(kt, 2, ps), if (st) stageA(kt, 1, ps), )
    DO_PHASE(3, if (st) stageA(kt, 3, ps), ,
             if (t == 14) { asm volatile("s_waitcnt vmcnt(0)" ::: "memory"); }
             else if (st) { asm volatile("s_waitcnt vmcnt(2)" ::: "memory"); })
  }
#undef DO_PHASE

  // ---- epilogue (R13): Q/K direct stores; V via LDS [col][s'] transpose ----
  const int s0g = m0 & 2047;
  const int bI  = m0 >> 11;
  char* VE = (char*)LDSX;

#pragma unroll
  for (int nf = 0; nf < 3; ++nf) {
    const int n = n0 + wc * 48 + nf * 16 + colL;
    const int which = n >> 10;
    const int c = n & 1023;
    const int h = c >> 6, d = c & 63;
    const float bias = ((which == 0) ? bq : (which == 1) ? bk : bv)[c];
    if (which == 2) {
      char* col = VE + (n - n0) * 528;
#pragma unroll
      for (int mf = 0; mf < 8; ++mf) {
        const int sl = wr * 128 + mf * 16 + rowg * 4;
        ushort4 o;
        o.x = f2bf(acc[mf][nf][0] + bias);
        o.y = f2bf(acc[mf][nf][1] + bias);
        o.z = f2bf(acc[mf][nf][2] + bias);
        o.w = f2bf(acc[mf][nf][3] + bias);
        *(ushort4*)(col + (((sl & ~63) | vperm(sl & 63)) * 2)) = o;
      }
    } else {
      ushort* dst = (which == 0) ? qws : kws;
      const int bh = bI * NH + h;
#pragma unroll
      for (int mf = 0; mf < 8; ++mf) {
        const int s = s0g + wr * 128 + mf * 16 + rowg * 4;
#pragma unroll
        for (int r = 0; r < 4; ++r)
          dst[((int64_t)bh * SS + s + r) * DH + d] = f2bf(acc[mf][nf][r] + bias);
      }
    }
  }

  if (n0 + 192 > 2048) {
    asm volatile("s_waitcnt lgkmcnt(0)" ::: "memory");
    __builtin_amdgcn_s_barrier();
    const int cv0 = (n0 >= 2048) ? 0 : (2048 - n0);
    const int nchunks = (192 - cv0) * 32;
    for (int idx = tid; idx < nchunks; idx += 512) {
      const int c  = cv0 + (idx >> 5);
      const int ch = idx & 31;
      uint4 v = *(const uint4*)(VE + c * 528 + ch * 16);
      const int n = n0 + c;
      const int cc = n & 1023;
      const int h = cc >> 6, d = cc & 63;
      *(uint4*)&vtws[((int64_t)(bI * NH + h) * DH + d) * SS + s0g + ch * 8] = v;
    }
  }
}

// ---------------- kernel 3: flash attention (8 waves, QBLK=256) --------------
// Same schedule/math as R13, at 512 threads: wave w owns q rows
// [q0+32w, q0+32w+32); stages 8 K-rows + 8 V-rows (1 gload each) + 1 mask
// chunk. Per-wave FIFO per step: V(t)1, K(t+1)1, V(t+1)1.
// Gates: after softmax vmcnt(2) -> V(t) landed; after PV vmcnt(1) -> K(t+1)
// landed (V(t+1) flies). LDS 40 KB -> 4 blocks/CU x 8 waves = 32 waves/CU.
__global__ __launch_bounds__(512, 8) void attn_kernel(
    const ushort* __restrict__ qws, const ushort* __restrict__ kws,
    const ushort* __restrict__ vtws, const float* __restrict__ maskL,
    float* __restrict__ out) {
  __shared__ short Kl[2][64][64];   // 16 KB
  __shared__ short Vl[2][64][64];   // 16 KB
  __shared__ float Ml[2048];        // 8 KB mask*log2e for this b

  const int tid = threadIdx.x, wid = tid >> 6, lane = tid & 63;
  const int bh = blockIdx.x, qb = blockIdx.y;
  const int b = bh >> 4, h = bh & 15;
  const int64_t qkb = (int64_t)bh * SS * DH;
  const int64_t vb  = (int64_t)bh * DH * SS;
  const int q0 = qb * 256;
  const int colL = lane & 15, rowg = lane >> 4;
  const float SCL = 0.125f * LOG2E;

  // ---- staging: wave w stages K rows / Vt rows [w*8, w*8+8), 1 gload each
  const int srow = wid * 8 + (lane >> 3);
  const int swzc = (((lane & 7) * 16) ^ ((lane >> 3) << 4)) >> 1;
  const ushort* gk = kws + qkb + (int64_t)srow * DH + swzc;
  const ushort* gv = vtws + vb + (int64_t)srow * SS + swzc;
  ushort* ldsK = (ushort*)&Kl[0][0][0] + wid * 512;
  ushort* ldsV = (ushort*)&Vl[0][0][0] + wid * 512;

  auto stageK = [&](int slot, int tt) {
    gload_lds16(gk + tt * 4096, ldsK + slot * 4096);
  };
  auto stageV = [&](int slot, int tt) {
    gload_lds16(gv + tt * 64, ldsV + slot * 4096);
  };
  auto stageMask = [&]() {
    const float* src = maskL + b * SS + wid * 256 + lane * 4;
    gload_lds16((const ushort*)src, (ushort*)(Ml + wid * 256));
  };

  const int xsw = (colL & 7) << 4;
  const char* kb0 = (const char*)&Kl[0][0][0] + colL * 128 + ((rowg * 16) ^ xsw);
  const char* kb1 = (const char*)&Kl[0][0][0] + colL * 128 + ((64 + rowg * 16) ^ xsw);
  const char* vb0 = (const char*)&Vl[0][0][0] + colL * 128 + ((rowg * 16) ^ xsw);
  const char* vb1 = (const char*)&Vl[0][0][0] + colL * 128 + ((64 + rowg * 16) ^ xsw);

  bf16x8 qf[2][2];
#pragma unroll
  for (int qh = 0; qh < 2; ++qh) {
    const ushort* gq = qws + qkb + (int64_t)(q0 + wid * 32 + qh * 16 + colL) * DH + rowg * 8;
    qf[qh][0] = *(const bf16x8*)(gq);
    qf[qh][1] = *(const bf16x8*)(gq + 32);
  }

  const f32x4 FZERO = {0.f, 0.f, 0.f, 0.f};
  union OU { uint32_t u[4]; bf16x8 v; } onesu;
  onesu.u[0] = 0x3F803F80u; onesu.u[1] = 0x3F803F80u;
  onesu.u[2] = 0x3F803F80u; onesu.u[3] = 0x3F803F80u;
  const bf16x8 ONES = onesu.v;

  f32x4 accO[2][4];
  f32x4 accL[2];
#pragma unroll
  for (int qh = 0; qh < 2; ++qh) {
    accL[qh] = FZERO;
#pragma unroll
    for (int dt = 0; dt < 4; ++dt)
#pragma unroll
      for (int r = 0; r < 4; ++r) accO[qh][dt][r] = 0.f;
  }

  // ---- prologue: mask(1), K0(1), V0(1); wait mask+K0, leave V0 in flight
  stageMask();
  stageK(0, 0);
  stageV(0, 0);
  asm volatile("s_waitcnt vmcnt(1)" ::: "memory");
  __builtin_amdgcn_s_barrier();

  for (int t = 0; t < 32; ++t) {
    const int cur = t & 1;
    const bool st = (t < 31);
    if (st) { stageK(cur ^ 1, t + 1); stageV(cur ^ 1, t + 1); }

    // ---- QK^T swapped, both q-halves share each K fragment
    f32x4 sc[2][4];
    __builtin_amdgcn_s_setprio(1);
#pragma unroll
    for (int kt = 0; kt < 4; ++kt) {
      bf16x8 kf0 = *(const bf16x8*)(kb0 + cur * 8192 + kt * 2048);
      bf16x8 kf1 = *(const bf16x8*)(kb1 + cur * 8192 + kt * 2048);
      sc[0][kt] = __builtin_amdgcn_mfma_f32_16x16x32_bf16(kf0, qf[0][0], FZERO, 0, 0, 0);
      sc[0][kt] = __builtin_amdgcn_mfma_f32_16x16x32_bf16(kf1, qf[0][1], sc[0][kt], 0, 0, 0);
      sc[1][kt] = __builtin_amdgcn_mfma_f32_16x16x32_bf16(kf0, qf[1][0], FZERO, 0, 0, 0);
      sc[1][kt] = __builtin_amdgcn_mfma_f32_16x16x32_bf16(kf1, qf[1][1], sc[1][kt], 0, 0, 0);
    }
    __builtin_amdgcn_s_setprio(0);

    // ---- softmax: P = exp2(sc*scale + maskL) with mask from LDS
    float4 m4[4];
#pragma unroll
    for (int kt = 0; kt < 4; ++kt)
      m4[kt] = *(const float4*)&Ml[t * 64 + kt * 16 + rowg * 4];

    bf16x8 paf[2][2];
#pragma unroll
    for (int qh = 0; qh < 2; ++qh) {
#pragma unroll
      for (int kt = 0; kt < 4; ++kt) {
        sc[qh][kt][0] = exp2_hw(fmaf(sc[qh][kt][0], SCL, m4[kt].x));
        sc[qh][kt][1] = exp2_hw(fmaf(sc[qh][kt][1], SCL, m4[kt].y));
        sc[qh][kt][2] = exp2_hw(fmaf(sc[qh][kt][2], SCL, m4[kt].z));
        sc[qh][kt][3] = exp2_hw(fmaf(sc[qh][kt][3], SCL, m4[kt].w));
      }
      union PU { uint32_t u[4]; bf16x8 v; } p0, p1;
      p0.u[0] = cvt_pk_bf16(sc[qh][0][0], sc[qh][0][1]);
      p0.u[1] = cvt_pk_bf16(sc[qh][0][2], sc[qh][0][3]);
      p0.u[2] = cvt_pk_bf16(sc[qh][1][0], sc[qh][1][1]);
      p0.u[3] = cvt_pk_bf16(sc[qh][1][2], sc[qh][1][3]);
      p1.u[0] = cvt_pk_bf16(sc[qh][2][0], sc[qh][2][1]);
      p1.u[1] = cvt_pk_bf16(sc[qh][2][2], sc[qh][2][3]);
      p1.u[2] = cvt_pk_bf16(sc[qh][3][0], sc[qh][3][1]);
      p1.u[3] = cvt_pk_bf16(sc[qh][3][2], sc[qh][3][3]);
      paf[qh][0] = p0.v;
      paf[qh][1] = p1.v;
    }

    // ---- gate V(t): counted (leaves K(t+1),V(t+1) in flight)
    if (st) { asm volatile("s_waitcnt vmcnt(2)" ::: "memory"); }
    else    { asm volatile("s_waitcnt vmcnt(0)" ::: "memory"); }
    __builtin_amdgcn_s_barrier();

    // ---- PV + row-sum
    __builtin_amdgcn_s_setprio(1);
#pragma unroll
    for (int ks = 0; ks < 2; ++ks) {
      accL[0] = __builtin_amdgcn_mfma_f32_16x16x32_bf16(paf[0][ks], ONES, accL[0], 0, 0, 0);
      accL[1] = __builtin_amdgcn_mfma_f32_16x16x32_bf16(paf[1][ks], ONES, accL[1], 0, 0, 0);
#pragma unroll
      for (int dt = 0; dt < 4; ++dt) {
        bf16x8 vf = *(const bf16x8*)((ks == 0 ? vb0 : vb1) + cur * 8192 + dt * 2048);
        accO[0][dt] = __builtin_amdgcn_mfma_f32_16x16x32_bf16(paf[0][ks], vf, accO[0][dt], 0, 0, 0);
        accO[1][dt] = __builtin_amdgcn_mfma_f32_16x16x32_bf16(paf[1][ks], vf, accO[1][dt], 0, 0, 0);
      }
    }
    __builtin_amdgcn_s_setprio(0);

    // ---- gate K(t+1): counted; V(t+1) stays in flight into step t+1
    if (st) {
      asm volatile("s_waitcnt vmcnt(1)" ::: "memory");
      __builtin_amdgcn_s_barrier();
    }
  }

#pragma unroll
  for (int qh = 0; qh < 2; ++qh) {
    float inv[4];
#pragma unroll
    for (int r = 0; r < 4; ++r) inv[r] = 1.0f / accL[qh][r];
#pragma unroll
    for (int dt = 0; dt < 4; ++dt)
#pragma unroll
      for (int r = 0; r < 4; ++r) {
        const int s = q0 + wid * 32 + qh * 16 + rowg * 4 + r;
        out[((int64_t)b * SS + s) * HID + h * DH + dt * 16 + colL] = accO[qh][dt][r] * inv[r];
      }
  }
}

// ---------------- launch -----------------------------------------------------
extern "C" void kernel_launch(void* const* d_in, const int* in_sizes, int n_in,
                              void* d_out, int out_size, void* d_ws, size_t ws_size,
                              hipStream_t stream) {
  const float* x  = (const float*)d_in[0];
  const float* am = (const float*)d_in[1];
  const float* wq = (const float*)d_in[2];
  const float* bq = (const float*)d_in[3];
  const float* wk = (const float*)d_in[4];
  const float* bk = (const float*)d_in[5];
  const float* wv = (const float*)d_in[6];
  const float* bv = (const float*)d_in[7];
  float* out = (float*)d_out;
  char* ws = (char*)d_ws;

  ushort* xbf  = (ushort*)(ws);                    // 16 MB
  ushort* wbf  = (ushort*)(ws + 16777216);         // 6 MB
  ushort* qws  = (ushort*)(ws + 23068672);         // 16 MB [bh][s][64]
  ushort* kws  = (ushort*)(ws + 39845888);         // 16 MB [bh][s][64]
  ushort* vtws = (ushort*)(ws + 56623104);         // 16 MB [bh][64][s] (tau-permuted per 64)
  float*  mskL = (float*)(ws + 73400320);          // 32 KB mask*log2e

  hipLaunchKernelGGL(cvt_kernel, dim3(11272), dim3(256), 0, stream,
                     x, wq, wk, wv, am, xbf, wbf, mskL);
  hipLaunchKernelGGL(qkv_gemm, dim3(512), dim3(512), 0, stream,
                     xbf, wbf, bq, bk, bv, qws, kws, vtws);
  hipLaunchKernelGGL(attn_kernel, dim3(64, 8), dim3(512), 0, stream,
                     qws, kws, vtws, mskL, out);
}

// Round 17
// 270.307 us; speedup vs baseline: 2.2986x; 2.2986x over previous
//
#include <hip/hip_runtime.h>
#include <stdint.h>

#define BB 4
#define SS 2048
#define HID 1024
#define NH 16
#define DH 64

using bf16x8 = __attribute__((ext_vector_type(8))) short;
using f32x4  = __attribute__((ext_vector_type(4))) float;

#define LOG2E 1.44269504088896340736f

__device__ __forceinline__ ushort f2bf(float f) {
  union { float f; uint32_t u; } v; v.f = f;
  return (ushort)((v.u + 0x7FFFu + ((v.u >> 16) & 1u)) >> 16);
}

__device__ __forceinline__ uint32_t cvt_pk_bf16(float a, float b) {
  uint32_t r;
  asm("v_cvt_pk_bf16_f32 %0, %1, %2" : "=v"(r) : "v"(a), "v"(b));
  return r;
}

__device__ __forceinline__ float exp2_hw(float x) {
  float r;
  asm("v_exp_f32 %0, %1" : "=v"(r) : "v"(x));
  return r;
}

__device__ __forceinline__ void gload_lds16(const ushort* g, ushort* l) {
  __builtin_amdgcn_global_load_lds(
      (const __attribute__((address_space(1))) uint32_t*)g,
      (__attribute__((address_space(3))) uint32_t*)l, 16, 0, 0);
}

// V-column permutation within each 64-key block (see attn P-packing):
// kk = [j5, j3, j2, j4, j1, j0]
__device__ __forceinline__ int vperm(int j) {
  return (j & 0x23) | ((j & 0x0C) << 1) | ((j & 0x10) >> 2);
}

// ---------------- kernel 1: f32 -> bf16 convert (X, W concat) + mask*log2e ---
__global__ void cvt_kernel(const float* __restrict__ x, const float* __restrict__ wq,
                           const float* __restrict__ wk, const float* __restrict__ wv,
                           const float* __restrict__ am,
                           ushort* __restrict__ xbf, ushort* __restrict__ wbf,
                           float* __restrict__ maskL) {
  const int64_t NX4 = (int64_t)BB * SS * HID / 4;   // 2097152
  const int64_t NW4 = (int64_t)HID * HID / 4;       // 262144 = 2^18
  const int64_t NWT = 3 * NW4;                      // 786432
  int64_t i = (int64_t)blockIdx.x * blockDim.x + threadIdx.x;
  if (i >= NX4 + NWT) {
    const int64_t jm = i - (NX4 + NWT);
    float4 v = ((const float4*)am)[jm];
    v.x *= LOG2E; v.y *= LOG2E; v.z *= LOG2E; v.w *= LOG2E;
    ((float4*)maskL)[jm] = v;
    return;
  }
  float4 v;
  ushort4* dst;
  if (i < NX4) {
    v = ((const float4*)x)[i];
    dst = (ushort4*)xbf + i;
  } else {
    int64_t j = i - NX4;
    int w = (int)(j >> 18);
    int64_t k = j & (NW4 - 1);
    const float* src = (w == 0) ? wq : (w == 1) ? wk : wv;
    v = ((const float4*)src)[k];
    dst = (ushort4*)wbf + j;
  }
  ushort4 o;
  o.x = f2bf(v.x); o.y = f2bf(v.y); o.z = f2bf(v.z); o.w = f2bf(v.w);
  *dst = o;
}

// ---------------- kernel 2: QKV projection GEMM (256x192, BK=64, 4-phase) ----
__global__ __launch_bounds__(512, 2) void qkv_gemm(
    const ushort* __restrict__ xbf, const ushort* __restrict__ wbf,
    const float* __restrict__ bq, const float* __restrict__ bk,
    const float* __restrict__ bv,
    ushort* __restrict__ qws, ushort* __restrict__ kws, ushort* __restrict__ vtws) {
  __shared__ __align__(16) char LDSX[114688];   // A: 64KB dbuf, B: 48KB dbuf

  const int tid = threadIdx.x, wid = tid >> 6, lane = tid & 63;
  const int colL = lane & 15, rowg = lane >> 4;
  const int wr = wid >> 2, wc = wid & 3;

  const int wgid = (blockIdx.x & 7) * 64 + (blockIdx.x >> 3);
  const int m0 = (wgid >> 4) * 256;
  const int n0 = (wgid & 15) * 192;

  const int swzcol = (((tid & 7) * 16) ^ (((tid >> 3) & 7) << 4)) >> 1;
  const ushort* aSrc = xbf + (int64_t)(m0 + (tid >> 3)) * HID + swzcol;
  const ushort* bSrc = wbf + (int64_t)(n0 + (tid >> 3)) * HID + swzcol;
  ushort* Al_u = (ushort*)LDSX;
  ushort* Bl_u = (ushort*)(LDSX + 65536);

  auto stageA = [&](int kt, int r, int ps) {
    gload_lds16(aSrc + r * 64 * HID + kt * 64, Al_u + ps * 16384 + r * 4096 + wid * 512);
  };
  auto stageB = [&](int kt, int r, int ps) {
    gload_lds16(bSrc + r * 64 * HID + kt * 64, Bl_u + ps * 12288 + r * 4096 + wid * 512);
  };

  const int xsw = (colL & 7) << 4;
  const int offk0 = (rowg * 16) ^ xsw;
  const int offk1 = (64 + rowg * 16) ^ xsw;
  const int arow = (wr * 128 + colL) * 128;
  const int brow = (wc * 48 + colL) * 128;
  const char* AlC = (const char*)LDSX;
  const char* BlC = (const char*)(LDSX + 65536);

  f32x4 acc[8][3];
#pragma unroll
  for (int i = 0; i < 8; ++i)
#pragma unroll
    for (int j = 0; j < 3; ++j)
#pragma unroll
      for (int r = 0; r < 4; ++r) acc[i][j][r] = 0.f;

  stageB(0, 0, 0); stageB(0, 1, 0); stageB(0, 2, 0);
  stageA(0, 0, 0); stageA(0, 2, 0); stageA(0, 1, 0); stageA(0, 3, 0);
  asm volatile("s_waitcnt vmcnt(2)" ::: "memory");
  __builtin_amdgcn_s_barrier();

#define DO_PHASE(P, S1, S2, PRE_BAR2)                                          \
  {                                                                            \
    const int mfa = 2 * (P), mfb = 2 * (P) + 1;                                \
    bf16x8 aA0 = *(const bf16x8*)(kA0 + mfa * 2048);                           \
    bf16x8 aA1 = *(const bf16x8*)(kA1 + mfa * 2048);                           \
    bf16x8 aB0 = *(const bf16x8*)(kA0 + mfb * 2048);                           \
    bf16x8 aB1 = *(const bf16x8*)(kA1 + mfb * 2048);                           \
    S1; S2;                                                                    \
    __builtin_amdgcn_s_setprio(1);                                             \
    _Pragma("unroll")                                                          \
    for (int nf = 0; nf < 3; ++nf) {                                           \
      acc[mfa][nf] = __builtin_amdgcn_mfma_f32_16x16x32_bf16(aA0, bfr[nf][0], acc[mfa][nf], 0, 0, 0); \
      acc[mfa][nf] = __builtin_amdgcn_mfma_f32_16x16x32_bf16(aA1, bfr[nf][1], acc[mfa][nf], 0, 0, 0); \
      acc[mfb][nf] = __builtin_amdgcn_mfma_f32_16x16x32_bf16(aB0, bfr[nf][0], acc[mfb][nf], 0, 0, 0); \
      acc[mfb][nf] = __builtin_amdgcn_mfma_f32_16x16x32_bf16(aB1, bfr[nf][1], acc[mfb][nf], 0, 0, 0); \
    }                                                                          \
    __builtin_amdgcn_s_setprio(0);                                             \
    PRE_BAR2;                                                                  \
    __builtin_amdgcn_s_barrier();                                              \
  }

  for (int t = 0; t < 16; ++t) {
    const int p = t & 1;
    const int ps = p ^ 1;
    const bool st = (t < 15);
    const int kt = t + 1;
    const char* kA0 = AlC + p * 32768 + arow + offk0;
    const char* kA1 = AlC + p * 32768 + arow + offk1;
    const char* kB0 = BlC + p * 24576 + brow + offk0;
    const char* kB1 = BlC + p * 24576 + brow + offk1;

    bf16x8 bfr[3][2];
#pragma unroll
    for (int nf = 0; nf < 3; ++nf) {
      bfr[nf][0] = *(const bf16x8*)(kB0 + nf * 2048);
      bfr[nf][1] = *(const bf16x8*)(kB1 + nf * 2048);
    }

    DO_PHASE(0, if (st) stageB(kt, 0, ps), if (st) stageB(kt, 1, ps), )
    DO_PHASE(1, if (st) stageB(kt, 2, ps), if (st) stageA(kt, 0, ps),
             if (t == 15) { asm volatile("s_waitcnt vmcnt(0)" ::: "memory"); }
             else        { asm volatile("s_waitcnt vmcnt(4)" ::: "memory"); })
    DO_PHASE(2, if (st) stageA(kt, 2, ps), if (st) stageA(kt, 1, ps), )
    DO_PHASE(3, if (st) stageA(kt, 3, ps), ,
             if (t == 14) { asm volatile("s_waitcnt vmcnt(0)" ::: "memory"); }
             else if (st) { asm volatile("s_waitcnt vmcnt(2)" ::: "memory"); })
  }
#undef DO_PHASE

  // ---- epilogue (R13): Q/K direct stores; V via LDS [col][s'] transpose ----
  const int s0g = m0 & 2047;
  const int bI  = m0 >> 11;
  char* VE = (char*)LDSX;

#pragma unroll
  for (int nf = 0; nf < 3; ++nf) {
    const int n = n0 + wc * 48 + nf * 16 + colL;
    const int which = n >> 10;
    const int c = n & 1023;
    const int h = c >> 6, d = c & 63;
    const float bias = ((which == 0) ? bq : (which == 1) ? bk : bv)[c];
    if (which == 2) {
      char* col = VE + (n - n0) * 528;
#pragma unroll
      for (int mf = 0; mf < 8; ++mf) {
        const int sl = wr * 128 + mf * 16 + rowg * 4;
        ushort4 o;
        o.x = f2bf(acc[mf][nf][0] + bias);
        o.y = f2bf(acc[mf][nf][1] + bias);
        o.z = f2bf(acc[mf][nf][2] + bias);
        o.w = f2bf(acc[mf][nf][3] + bias);
        *(ushort4*)(col + (((sl & ~63) | vperm(sl & 63)) * 2)) = o;
      }
    } else {
      ushort* dst = (which == 0) ? qws : kws;
      const int bh = bI * NH + h;
#pragma unroll
      for (int mf = 0; mf < 8; ++mf) {
        const int s = s0g + wr * 128 + mf * 16 + rowg * 4;
#pragma unroll
        for (int r = 0; r < 4; ++r)
          dst[((int64_t)bh * SS + s + r) * DH + d] = f2bf(acc[mf][nf][r] + bias);
      }
    }
  }

  if (n0 + 192 > 2048) {
    asm volatile("s_waitcnt lgkmcnt(0)" ::: "memory");
    __builtin_amdgcn_s_barrier();
    const int cv0 = (n0 >= 2048) ? 0 : (2048 - n0);
    const int nchunks = (192 - cv0) * 32;
    for (int idx = tid; idx < nchunks; idx += 512) {
      const int c  = cv0 + (idx >> 5);
      const int ch = idx & 31;
      uint4 v = *(const uint4*)(VE + c * 528 + ch * 16);
      const int n = n0 + c;
      const int cc = n & 1023;
      const int h = cc >> 6, d = cc & 63;
      *(uint4*)&vtws[((int64_t)(bI * NH + h) * DH + d) * SS + s0g + ch * 8] = v;
    }
  }
}

// ---------------- kernel 3: flash attention (counted split; mask via L2) -----
// R13 schedule at 256 threads, LDS = K/V only (32768 B exactly -> up to
// 5 blocks/CU if regs fit). Mask read as plain float4 global loads (32 KB,
// L2-hot), double-buffered mC/mN via static 2-step unroll. Counted gates
// remain sound with extra mask loads in the vm queue (they only make the
// waits more conservative; compiler inserts its own waits before mask use).
__global__ __launch_bounds__(256, 4) void attn_kernel(
    const ushort* __restrict__ qws, const ushort* __restrict__ kws,
    const ushort* __restrict__ vtws, const float* __restrict__ maskL,
    float* __restrict__ out) {
  __shared__ short Kl[2][64][64];   // 16 KB
  __shared__ short Vl[2][64][64];   // 16 KB

  const int tid = threadIdx.x, wid = tid >> 6, lane = tid & 63;
  const int bh = blockIdx.x, qb = blockIdx.y;
  const int b = bh >> 4, h = bh & 15;
  const int64_t qkb = (int64_t)bh * SS * DH;
  const int64_t vb  = (int64_t)bh * DH * SS;
  const int q0 = qb * 128;
  const int colL = lane & 15, rowg = lane >> 4;
  const float SCL = 0.125f * LOG2E;

  const int srow = wid * 16 + (lane >> 3);
  const int swzc = (((lane & 7) * 16) ^ ((lane >> 3) << 4)) >> 1;
  const ushort* gk = kws + qkb + (int64_t)srow * DH + swzc;
  const ushort* gv = vtws + vb + (int64_t)srow * SS + swzc;
  ushort* ldsK = (ushort*)&Kl[0][0][0] + wid * 1024;
  ushort* ldsV = (ushort*)&Vl[0][0][0] + wid * 1024;

  auto stageK = [&](int slot, int tt) {
    const ushort* k0 = gk + tt * 4096;
    gload_lds16(k0,       ldsK + slot * 4096);
    gload_lds16(k0 + 512, ldsK + slot * 4096 + 512);
  };
  auto stageV = [&](int slot, int tt) {
    const ushort* v0 = gv + tt * 64;
    gload_lds16(v0,          ldsV + slot * 4096);
    gload_lds16(v0 + 8 * SS, ldsV + slot * 4096 + 512);
  };

  const int xsw = (colL & 7) << 4;
  const char* kb0 = (const char*)&Kl[0][0][0] + colL * 128 + ((rowg * 16) ^ xsw);
  const char* kb1 = (const char*)&Kl[0][0][0] + colL * 128 + ((64 + rowg * 16) ^ xsw);
  const char* vb0 = (const char*)&Vl[0][0][0] + colL * 128 + ((rowg * 16) ^ xsw);
  const char* vb1 = (const char*)&Vl[0][0][0] + colL * 128 + ((64 + rowg * 16) ^ xsw);

  bf16x8 qf[2][2];
#pragma unroll
  for (int qh = 0; qh < 2; ++qh) {
    const ushort* gq = qws + qkb + (int64_t)(q0 + wid * 32 + qh * 16 + colL) * DH + rowg * 8;
    qf[qh][0] = *(const bf16x8*)(gq);
    qf[qh][1] = *(const bf16x8*)(gq + 32);
  }

  const f32x4 FZERO = {0.f, 0.f, 0.f, 0.f};
  union OU { uint32_t u[4]; bf16x8 v; } onesu;
  onesu.u[0] = 0x3F803F80u; onesu.u[1] = 0x3F803F80u;
  onesu.u[2] = 0x3F803F80u; onesu.u[3] = 0x3F803F80u;
  const bf16x8 ONES = onesu.v;

  f32x4 accO[2][4];
  f32x4 accL[2];
#pragma unroll
  for (int qh = 0; qh < 2; ++qh) {
    accL[qh] = FZERO;
#pragma unroll
    for (int dt = 0; dt < 4; ++dt)
#pragma unroll
      for (int r = 0; r < 4; ++r) accO[qh][dt][r] = 0.f;
  }

  // mask pointer: float4 index = t*16 + kt*4 + rowg
  const float4* mp = (const float4*)(maskL + b * SS) + rowg;
  float4 mC[4], mN[4];

  // ---- prologue: mask(plain), K0(2), V0(2); gate leaves V0 in flight
#pragma unroll
  for (int kt = 0; kt < 4; ++kt) mC[kt] = mp[kt * 4];
  stageK(0, 0);
  stageV(0, 0);
  asm volatile("s_waitcnt vmcnt(2)" ::: "memory");
  __builtin_amdgcn_s_barrier();

#define ATTN_STEP(T, CUR, MUSE, MLOAD, ST)                                     \
  {                                                                            \
    if (ST) {                                                                  \
      stageK((CUR) ^ 1, (T) + 1);                                              \
      stageV((CUR) ^ 1, (T) + 1);                                              \
      _Pragma("unroll")                                                        \
      for (int kt = 0; kt < 4; ++kt)                                           \
        MLOAD[kt] = mp[((T) + 1) * 16 + kt * 4];                               \
    }                                                                          \
    f32x4 sc[2][4];                                                            \
    __builtin_amdgcn_s_setprio(1);                                             \
    _Pragma("unroll")                                                          \
    for (int kt = 0; kt < 4; ++kt) {                                           \
      bf16x8 kf0 = *(const bf16x8*)(kb0 + (CUR) * 8192 + kt * 2048);           \
      bf16x8 kf1 = *(const bf16x8*)(kb1 + (CUR) * 8192 + kt * 2048);           \
      sc[0][kt] = __builtin_amdgcn_mfma_f32_16x16x32_bf16(kf0, qf[0][0], FZERO, 0, 0, 0); \
      sc[0][kt] = __builtin_amdgcn_mfma_f32_16x16x32_bf16(kf1, qf[0][1], sc[0][kt], 0, 0, 0); \
      sc[1][kt] = __builtin_amdgcn_mfma_f32_16x16x32_bf16(kf0, qf[1][0], FZERO, 0, 0, 0); \
      sc[1][kt] = __builtin_amdgcn_mfma_f32_16x16x32_bf16(kf1, qf[1][1], sc[1][kt], 0, 0, 0); \
    }                                                                          \
    __builtin_amdgcn_s_setprio(0);                                             \
    bf16x8 paf[2][2];                                                          \
    _Pragma("unroll")                                                          \
    for (int qh = 0; qh < 2; ++qh) {                                           \
      _Pragma("unroll")                                                        \
      for (int kt = 0; kt < 4; ++kt) {                                         \
        sc[qh][kt][0] = exp2_hw(fmaf(sc[qh][kt][0], SCL, MUSE[kt].x));         \
        sc[qh][kt][1] = exp2_hw(fmaf(sc[qh][kt][1], SCL, MUSE[kt].y));         \
        sc[qh][kt][2] = exp2_hw(fmaf(sc[qh][kt][2], SCL, MUSE[kt].z));         \
        sc[qh][kt][3] = exp2_hw(fmaf(sc[qh][kt][3], SCL, MUSE[kt].w));         \
      }                                                                        \
      union PU { uint32_t u[4]; bf16x8 v; } p0, p1;                            \
      p0.u[0] = cvt_pk_bf16(sc[qh][0][0], sc[qh][0][1]);                       \
      p0.u[1] = cvt_pk_bf16(sc[qh][0][2], sc[qh][0][3]);                       \
      p0.u[2] = cvt_pk_bf16(sc[qh][1][0], sc[qh][1][1]);                       \
      p0.u[3] = cvt_pk_bf16(sc[qh][1][2], sc[qh][1][3]);                       \
      p1.u[0] = cvt_pk_bf16(sc[qh][2][0], sc[qh][2][1]);                       \
      p1.u[1] = cvt_pk_bf16(sc[qh][2][2], sc[qh][2][3]);                       \
      p1.u[2] = cvt_pk_bf16(sc[qh][3][0], sc[qh][3][1]);                       \
      p1.u[3] = cvt_pk_bf16(sc[qh][3][2], sc[qh][3][3]);                       \
      paf[qh][0] = p0.v;                                                       \
      paf[qh][1] = p1.v;                                                       \
    }                                                                          \
    if (ST) { asm volatile("s_waitcnt vmcnt(4)" ::: "memory"); }               \
    else    { asm volatile("s_waitcnt vmcnt(0)" ::: "memory"); }               \
    __builtin_amdgcn_s_barrier();                                              \
    __builtin_amdgcn_s_setprio(1);                                             \
    _Pragma("unroll")                                                          \
    for (int ks = 0; ks < 2; ++ks) {                                           \
      accL[0] = __builtin_amdgcn_mfma_f32_16x16x32_bf16(paf[0][ks], ONES, accL[0], 0, 0, 0); \
      accL[1] = __builtin_amdgcn_mfma_f32_16x16x32_bf16(paf[1][ks], ONES, accL[1], 0, 0, 0); \
      _Pragma("unroll")                                                        \
      for (int dt = 0; dt < 4; ++dt) {                                         \
        bf16x8 vf = *(const bf16x8*)((ks == 0 ? vb0 : vb1) + (CUR) * 8192 + dt * 2048); \
        accO[0][dt] = __builtin_amdgcn_mfma_f32_16x16x32_bf16(paf[0][ks], vf, accO[0][dt], 0, 0, 0); \
        accO[1][dt] = __builtin_amdgcn_mfma_f32_16x16x32_bf16(paf[1][ks], vf, accO[1][dt], 0, 0, 0); \
      }                                                                        \
    }                                                                          \
    __builtin_amdgcn_s_setprio(0);                                             \
    if (ST) {                                                                  \
      asm volatile("s_waitcnt vmcnt(2)" ::: "memory");                         \
      __builtin_amdgcn_s_barrier();                                            \
    }                                                                          \
  }

  for (int t = 0; t < 32; t += 2) {
    ATTN_STEP(t,     0, mC, mN, true)
    ATTN_STEP(t + 1, 1, mN, mC, (t + 1 < 31))
  }
#undef ATTN_STEP

#pragma unroll
  for (int qh = 0; qh < 2; ++qh) {
    float inv[4];
#pragma unroll
    for (int r = 0; r < 4; ++r) inv[r] = 1.0f / accL[qh][r];
#pragma unroll
    for (int dt = 0; dt < 4; ++dt)
#pragma unroll
      for (int r = 0; r < 4; ++r) {
        const int s = q0 + wid * 32 + qh * 16 + rowg * 4 + r;
        out[((int64_t)b * SS + s) * HID + h * DH + dt * 16 + colL] = accO[qh][dt][r] * inv[r];
      }
  }
}

// ---------------- launch -----------------------------------------------------
extern "C" void kernel_launch(void* const* d_in, const int* in_sizes, int n_in,
                              void* d_out, int out_size, void* d_ws, size_t ws_size,
                              hipStream_t stream) {
  const float* x  = (const float*)d_in[0];
  const float* am = (const float*)d_in[1];
  const float* wq = (const float*)d_in[2];
  const float* bq = (const float*)d_in[3];
  const float* wk = (const float*)d_in[4];
  const float* bk = (const float*)d_in[5];
  const float* wv = (const float*)d_in[6];
  const float* bv = (const float*)d_in[7];
  float* out = (float*)d_out;
  char* ws = (char*)d_ws;

  ushort* xbf  = (ushort*)(ws);                    // 16 MB
  ushort* wbf  = (ushort*)(ws + 16777216);         // 6 MB
  ushort* qws  = (ushort*)(ws + 23068672);         // 16 MB [bh][s][64]
  ushort* kws  = (ushort*)(ws + 39845888);         // 16 MB [bh][s][64]
  ushort* vtws = (ushort*)(ws + 56623104);         // 16 MB [bh][64][s] (tau-permuted per 64)
  float*  mskL = (float*)(ws + 73400320);          // 32 KB mask*log2e

  hipLaunchKernelGGL(cvt_kernel, dim3(11272), dim3(256), 0, stream,
                     x, wq, wk, wv, am, xbf, wbf, mskL);
  hipLaunchKernelGGL(qkv_gemm, dim3(512), dim3(512), 0, stream,
                     xbf, wbf, bq, bk, bv, qws, kws, vtws);
  hipLaunchKernelGGL(attn_kernel, dim3(64, 16), dim3(256), 0, stream,
                     qws, kws, vtws, mskL, out);
}

// Round 18
// 148.877 us; speedup vs baseline: 4.1734x; 1.8156x over previous
//
#include <hip/hip_runtime.h>
#include <stdint.h>

#define BB 4
#define SS 2048
#define HID 1024
#define NH 16
#define DH 64

using bf16x8 = __attribute__((ext_vector_type(8))) short;
using f32x4  = __attribute__((ext_vector_type(4))) float;

#define LOG2E 1.44269504088896340736f

__device__ __forceinline__ ushort f2bf(float f) {
  union { float f; uint32_t u; } v; v.f = f;
  return (ushort)((v.u + 0x7FFFu + ((v.u >> 16) & 1u)) >> 16);
}

__device__ __forceinline__ uint32_t cvt_pk_bf16(float a, float b) {
  uint32_t r;
  asm("v_cvt_pk_bf16_f32 %0, %1, %2" : "=v"(r) : "v"(a), "v"(b));
  return r;
}

__device__ __forceinline__ float exp2_hw(float x) {
  float r;
  asm("v_exp_f32 %0, %1" : "=v"(r) : "v"(x));
  return r;
}

__device__ __forceinline__ void gload_lds16(const ushort* g, ushort* l) {
  __builtin_amdgcn_global_load_lds(
      (const __attribute__((address_space(1))) uint32_t*)g,
      (__attribute__((address_space(3))) uint32_t*)l, 16, 0, 0);
}

// V-column permutation within each 64-key block (see attn P-packing):
// kk = [j5, j3, j2, j4, j1, j0]
__device__ __forceinline__ int vperm(int j) {
  return (j & 0x23) | ((j & 0x0C) << 1) | ((j & 0x10) >> 2);
}

// ---------------- kernel 1: f32 -> bf16 convert (X, W concat) + mask*log2e ---
__global__ void cvt_kernel(const float* __restrict__ x, const float* __restrict__ wq,
                           const float* __restrict__ wk, const float* __restrict__ wv,
                           const float* __restrict__ am,
                           ushort* __restrict__ xbf, ushort* __restrict__ wbf,
                           float* __restrict__ maskL) {
  const int64_t NX4 = (int64_t)BB * SS * HID / 4;   // 2097152
  const int64_t NW4 = (int64_t)HID * HID / 4;       // 262144 = 2^18
  const int64_t NWT = 3 * NW4;                      // 786432
  int64_t i = (int64_t)blockIdx.x * blockDim.x + threadIdx.x;
  if (i >= NX4 + NWT) {
    const int64_t jm = i - (NX4 + NWT);
    float4 v = ((const float4*)am)[jm];
    v.x *= LOG2E; v.y *= LOG2E; v.z *= LOG2E; v.w *= LOG2E;
    ((float4*)maskL)[jm] = v;
    return;
  }
  float4 v;
  ushort4* dst;
  if (i < NX4) {
    v = ((const float4*)x)[i];
    dst = (ushort4*)xbf + i;
  } else {
    int64_t j = i - NX4;
    int w = (int)(j >> 18);
    int64_t k = j & (NW4 - 1);
    const float* src = (w == 0) ? wq : (w == 1) ? wk : wv;
    v = ((const float4*)src)[k];
    dst = (ushort4*)wbf + j;
  }
  ushort4 o;
  o.x = f2bf(v.x); o.y = f2bf(v.y); o.z = f2bf(v.z); o.w = f2bf(v.w);
  *dst = o;
}

// ---------------- kernel 2: QKV projection GEMM (256x192, BK=64, 8-phase) ----
// V-epilogue routed through LDS transpose for coalesced [d][s] stores.
__global__ __launch_bounds__(512, 2) void qkv_gemm(
    const ushort* __restrict__ xbf, const ushort* __restrict__ wbf,
    const float* __restrict__ bq, const float* __restrict__ bk,
    const float* __restrict__ bv,
    ushort* __restrict__ qws, ushort* __restrict__ kws, ushort* __restrict__ vtws) {
  __shared__ __align__(16) char LDSX[114688];   // A: 64KB dbuf, B: 48KB dbuf

  const int tid = threadIdx.x, wid = tid >> 6, lane = tid & 63;
  const int colL = lane & 15, rowg = lane >> 4;
  const int wr = wid >> 2, wc = wid & 3;

  const int wgid = (blockIdx.x & 7) * 64 + (blockIdx.x >> 3);
  const int m0 = (wgid >> 4) * 256;
  const int n0 = (wgid & 15) * 192;

  const int swzcol = (((tid & 7) * 16) ^ (((tid >> 3) & 7) << 4)) >> 1;
  const ushort* aSrc = xbf + (int64_t)(m0 + (tid >> 3)) * HID + swzcol;
  const ushort* bSrc = wbf + (int64_t)(n0 + (tid >> 3)) * HID + swzcol;
  ushort* Al_u = (ushort*)LDSX;
  ushort* Bl_u = (ushort*)(LDSX + 65536);

  auto stageA = [&](int kt, int r, int ps) {
    gload_lds16(aSrc + r * 64 * HID + kt * 64, Al_u + ps * 16384 + r * 4096 + wid * 512);
  };
  auto stageB = [&](int kt, int r, int ps) {
    gload_lds16(bSrc + r * 64 * HID + kt * 64, Bl_u + ps * 12288 + r * 4096 + wid * 512);
  };

  const int xsw = (colL & 7) << 4;
  const int offk0 = (rowg * 16) ^ xsw;
  const int offk1 = (64 + rowg * 16) ^ xsw;
  const int arow = (wr * 128 + colL) * 128;
  const int brow = (wc * 48 + colL) * 128;
  const char* AlC = (const char*)LDSX;
  const char* BlC = (const char*)(LDSX + 65536);

  f32x4 acc[8][3];
#pragma unroll
  for (int i = 0; i < 8; ++i)
#pragma unroll
    for (int j = 0; j < 3; ++j)
#pragma unroll
      for (int r = 0; r < 4; ++r) acc[i][j][r] = 0.f;

  stageB(0, 0, 0); stageB(0, 1, 0); stageB(0, 2, 0);
  stageA(0, 0, 0); stageA(0, 2, 0); stageA(0, 1, 0); stageA(0, 3, 0);
  asm volatile("s_waitcnt vmcnt(2)" ::: "memory");
  __builtin_amdgcn_s_barrier();

#define DO_PHASE(P, S1, S2, PRE_BAR2)                                          \
  {                                                                            \
    const int mfa = 2 * (P), mfb = 2 * (P) + 1;                                \
    bf16x8 aA0 = *(const bf16x8*)(kA0 + mfa * 2048);                           \
    bf16x8 aA1 = *(const bf16x8*)(kA1 + mfa * 2048);                           \
    bf16x8 aB0 = *(const bf16x8*)(kA0 + mfb * 2048);                           \
    bf16x8 aB1 = *(const bf16x8*)(kA1 + mfb * 2048);                           \
    S1; S2;                                                                    \
    __builtin_amdgcn_s_barrier();                                              \
    __builtin_amdgcn_s_setprio(1);                                             \
    _Pragma("unroll")                                                          \
    for (int nf = 0; nf < 3; ++nf) {                                           \
      acc[mfa][nf] = __builtin_amdgcn_mfma_f32_16x16x32_bf16(aA0, bfr[nf][0], acc[mfa][nf], 0, 0, 0); \
      acc[mfa][nf] = __builtin_amdgcn_mfma_f32_16x16x32_bf16(aA1, bfr[nf][1], acc[mfa][nf], 0, 0, 0); \
      acc[mfb][nf] = __builtin_amdgcn_mfma_f32_16x16x32_bf16(aB0, bfr[nf][0], acc[mfb][nf], 0, 0, 0); \
      acc[mfb][nf] = __builtin_amdgcn_mfma_f32_16x16x32_bf16(aB1, bfr[nf][1], acc[mfb][nf], 0, 0, 0); \
    }                                                                          \
    __builtin_amdgcn_s_setprio(0);                                             \
    PRE_BAR2;                                                                  \
    __builtin_amdgcn_s_barrier();                                              \
  }

  for (int t = 0; t < 16; ++t) {
    const int p = t & 1;
    const int ps = p ^ 1;
    const bool st = (t < 15);
    const int kt = t + 1;
    const char* kA0 = AlC + p * 32768 + arow + offk0;
    const char* kA1 = AlC + p * 32768 + arow + offk1;
    const char* kB0 = BlC + p * 24576 + brow + offk0;
    const char* kB1 = BlC + p * 24576 + brow + offk1;

    bf16x8 bfr[3][2];
#pragma unroll
    for (int nf = 0; nf < 3; ++nf) {
      bfr[nf][0] = *(const bf16x8*)(kB0 + nf * 2048);
      bfr[nf][1] = *(const bf16x8*)(kB1 + nf * 2048);
    }

    DO_PHASE(0, if (st) stageB(kt, 0, ps), if (st) stageB(kt, 1, ps), )
    DO_PHASE(1, if (st) stageB(kt, 2, ps), if (st) stageA(kt, 0, ps),
             if (t == 15) { asm volatile("s_waitcnt vmcnt(0)" ::: "memory"); }
             else        { asm volatile("s_waitcnt vmcnt(4)" ::: "memory"); })
    DO_PHASE(2, if (st) stageA(kt, 2, ps), if (st) stageA(kt, 1, ps), )
    DO_PHASE(3, if (st) stageA(kt, 3, ps), ,
             if (t == 14) { asm volatile("s_waitcnt vmcnt(0)" ::: "memory"); }
             else if (st) { asm volatile("s_waitcnt vmcnt(2)" ::: "memory"); })
  }
#undef DO_PHASE

  // ---- epilogue: Q/K direct stores; V via LDS [col][s'] transpose ----------
  const int s0g = m0 & 2047;
  const int bI  = m0 >> 11;
  char* VE = (char*)LDSX;                      // 192 cols x 528 B = 101376 B

#pragma unroll
  for (int nf = 0; nf < 3; ++nf) {
    const int n = n0 + wc * 48 + nf * 16 + colL;
    const int which = n >> 10;
    const int c = n & 1023;
    const int h = c >> 6, d = c & 63;
    const float bias = ((which == 0) ? bq : (which == 1) ? bk : bv)[c];
    if (which == 2) {
      char* col = VE + (n - n0) * 528;
#pragma unroll
      for (int mf = 0; mf < 8; ++mf) {
        const int sl = wr * 128 + mf * 16 + rowg * 4;
        ushort4 o;
        o.x = f2bf(acc[mf][nf][0] + bias);
        o.y = f2bf(acc[mf][nf][1] + bias);
        o.z = f2bf(acc[mf][nf][2] + bias);
        o.w = f2bf(acc[mf][nf][3] + bias);
        *(ushort4*)(col + (((sl & ~63) | vperm(sl & 63)) * 2)) = o;
      }
    } else {
      ushort* dst = (which == 0) ? qws : kws;
      const int bh = bI * NH + h;
#pragma unroll
      for (int mf = 0; mf < 8; ++mf) {
        const int s = s0g + wr * 128 + mf * 16 + rowg * 4;
#pragma unroll
        for (int r = 0; r < 4; ++r)
          dst[((int64_t)bh * SS + s + r) * DH + d] = f2bf(acc[mf][nf][r] + bias);
      }
    }
  }

  if (n0 + 192 > 2048) {
    asm volatile("s_waitcnt lgkmcnt(0)" ::: "memory");
    __builtin_amdgcn_s_barrier();
    const int cv0 = (n0 >= 2048) ? 0 : (2048 - n0);
    const int nchunks = (192 - cv0) * 32;
    for (int idx = tid; idx < nchunks; idx += 512) {
      const int c  = cv0 + (idx >> 5);
      const int ch = idx & 31;
      uint4 v = *(const uint4*)(VE + c * 528 + ch * 16);
      const int n = n0 + c;
      const int cc = n & 1023;
      const int h = cc >> 6, d = cc & 63;
      *(uint4*)&vtws[((int64_t)(bI * NH + h) * DH + d) * SS + s0g + ch * 8] = v;
    }
  }
}

// ---------------- kernel 3: flash attention (R13 verbatim: counted split) ----
// Per step t (FIFO outstanding at top after issue: V(t)2,K(t+1)2,V(t+1)2):
//   issue K(t+1),V(t+1) ; QK(t) ; softmax(t) ;
//   vmcnt(4) -> V(t) landed ; s_barrier ; PV(t) ;
//   vmcnt(2) -> K(t+1) landed ; s_barrier      (V(t+1) stays in flight)
// Mask in LDS (staged once via gload_lds -> vm queue stays pure/counted).
__global__ __launch_bounds__(256, 4) void attn_kernel(
    const ushort* __restrict__ qws, const ushort* __restrict__ kws,
    const ushort* __restrict__ vtws, const float* __restrict__ maskL,
    float* __restrict__ out) {
  __shared__ short Kl[2][64][64];   // 16 KB
  __shared__ short Vl[2][64][64];   // 16 KB
  __shared__ float Ml[2048];        // 8 KB mask*log2e for this b

  const int tid = threadIdx.x, wid = tid >> 6, lane = tid & 63;
  const int bh = blockIdx.x, qb = blockIdx.y;
  const int b = bh >> 4, h = bh & 15;
  const int64_t qkb = (int64_t)bh * SS * DH;
  const int64_t vb  = (int64_t)bh * DH * SS;
  const int q0 = qb * 128;
  const int colL = lane & 15, rowg = lane >> 4;
  const float SCL = 0.125f * LOG2E;

  const int srow = wid * 16 + (lane >> 3);
  const int swzc = (((lane & 7) * 16) ^ ((lane >> 3) << 4)) >> 1;
  const ushort* gk = kws + qkb + (int64_t)srow * DH + swzc;
  const ushort* gv = vtws + vb + (int64_t)srow * SS + swzc;
  ushort* ldsK = (ushort*)&Kl[0][0][0] + wid * 1024;
  ushort* ldsV = (ushort*)&Vl[0][0][0] + wid * 1024;

  auto stageK = [&](int slot, int tt) {
    const ushort* k0 = gk + tt * 4096;
    gload_lds16(k0,       ldsK + slot * 4096);
    gload_lds16(k0 + 512, ldsK + slot * 4096 + 512);
  };
  auto stageV = [&](int slot, int tt) {
    const ushort* v0 = gv + tt * 64;
    gload_lds16(v0,          ldsV + slot * 4096);
    gload_lds16(v0 + 8 * SS, ldsV + slot * 4096 + 512);
  };
  auto stageMask = [&]() {
    const float* src = maskL + b * SS + (wid * 2) * 256 + lane * 4;
    gload_lds16((const ushort*)src,         (ushort*)(Ml + wid * 2 * 256));
    gload_lds16((const ushort*)(src + 256), (ushort*)(Ml + wid * 2 * 256 + 256));
  };

  const int xsw = (colL & 7) << 4;
  const char* kb0 = (const char*)&Kl[0][0][0] + colL * 128 + ((rowg * 16) ^ xsw);
  const char* kb1 = (const char*)&Kl[0][0][0] + colL * 128 + ((64 + rowg * 16) ^ xsw);
  const char* vb0 = (const char*)&Vl[0][0][0] + colL * 128 + ((rowg * 16) ^ xsw);
  const char* vb1 = (const char*)&Vl[0][0][0] + colL * 128 + ((64 + rowg * 16) ^ xsw);

  bf16x8 qf[2][2];
#pragma unroll
  for (int qh = 0; qh < 2; ++qh) {
    const ushort* gq = qws + qkb + (int64_t)(q0 + wid * 32 + qh * 16 + colL) * DH + rowg * 8;
    qf[qh][0] = *(const bf16x8*)(gq);
    qf[qh][1] = *(const bf16x8*)(gq + 32);
  }

  const f32x4 FZERO = {0.f, 0.f, 0.f, 0.f};
  union OU { uint32_t u[4]; bf16x8 v; } onesu;
  onesu.u[0] = 0x3F803F80u; onesu.u[1] = 0x3F803F80u;
  onesu.u[2] = 0x3F803F80u; onesu.u[3] = 0x3F803F80u;
  const bf16x8 ONES = onesu.v;

  f32x4 accO[2][4];
  f32x4 accL[2];
#pragma unroll
  for (int qh = 0; qh < 2; ++qh) {
    accL[qh] = FZERO;
#pragma unroll
    for (int dt = 0; dt < 4; ++dt)
#pragma unroll
      for (int r = 0; r < 4; ++r) accO[qh][dt][r] = 0.f;
  }

  // ---- prologue: mask(2), K0(2), V0(2); wait mask+K0, leave V0 in flight
  stageMask();
  stageK(0, 0);
  stageV(0, 0);
  asm volatile("s_waitcnt vmcnt(2)" ::: "memory");
  __builtin_amdgcn_s_barrier();

  for (int t = 0; t < 32; ++t) {
    const int cur = t & 1;
    const bool st = (t < 31);
    if (st) { stageK(cur ^ 1, t + 1); stageV(cur ^ 1, t + 1); }

    // ---- QK^T swapped, both q-halves share each K fragment
    f32x4 sc[2][4];
    __builtin_amdgcn_s_setprio(1);
#pragma unroll
    for (int kt = 0; kt < 4; ++kt) {
      bf16x8 kf0 = *(const bf16x8*)(kb0 + cur * 8192 + kt * 2048);
      bf16x8 kf1 = *(const bf16x8*)(kb1 + cur * 8192 + kt * 2048);
      sc[0][kt] = __builtin_amdgcn_mfma_f32_16x16x32_bf16(kf0, qf[0][0], FZERO, 0, 0, 0);
      sc[0][kt] = __builtin_amdgcn_mfma_f32_16x16x32_bf16(kf1, qf[0][1], sc[0][kt], 0, 0, 0);
      sc[1][kt] = __builtin_amdgcn_mfma_f32_16x16x32_bf16(kf0, qf[1][0], FZERO, 0, 0, 0);
      sc[1][kt] = __builtin_amdgcn_mfma_f32_16x16x32_bf16(kf1, qf[1][1], sc[1][kt], 0, 0, 0);
    }
    __builtin_amdgcn_s_setprio(0);

    // ---- softmax: P = exp2(sc*scale + maskL) with mask from LDS
    float4 m4[4];
#pragma unroll
    for (int kt = 0; kt < 4; ++kt)
      m4[kt] = *(const float4*)&Ml[t * 64 + kt * 16 + rowg * 4];

    bf16x8 paf[2][2];
#pragma unroll
    for (int qh = 0; qh < 2; ++qh) {
#pragma unroll
      for (int kt = 0; kt < 4; ++kt) {
        sc[qh][kt][0] = exp2_hw(fmaf(sc[qh][kt][0], SCL, m4[kt].x));
        sc[qh][kt][1] = exp2_hw(fmaf(sc[qh][kt][1], SCL, m4[kt].y));
        sc[qh][kt][2] = exp2_hw(fmaf(sc[qh][kt][2], SCL, m4[kt].z));
        sc[qh][kt][3] = exp2_hw(fmaf(sc[qh][kt][3], SCL, m4[kt].w));
      }
      union PU { uint32_t u[4]; bf16x8 v; } p0, p1;
      p0.u[0] = cvt_pk_bf16(sc[qh][0][0], sc[qh][0][1]);
      p0.u[1] = cvt_pk_bf16(sc[qh][0][2], sc[qh][0][3]);
      p0.u[2] = cvt_pk_bf16(sc[qh][1][0], sc[qh][1][1]);
      p0.u[3] = cvt_pk_bf16(sc[qh][1][2], sc[qh][1][3]);
      p1.u[0] = cvt_pk_bf16(sc[qh][2][0], sc[qh][2][1]);
      p1.u[1] = cvt_pk_bf16(sc[qh][2][2], sc[qh][2][3]);
      p1.u[2] = cvt_pk_bf16(sc[qh][3][0], sc[qh][3][1]);
      p1.u[3] = cvt_pk_bf16(sc[qh][3][2], sc[qh][3][3]);
      paf[qh][0] = p0.v;
      paf[qh][1] = p1.v;
    }

    // ---- gate V(t): counted (leaves K(t+1),V(t+1) in flight)
    if (st) { asm volatile("s_waitcnt vmcnt(4)" ::: "memory"); }
    else    { asm volatile("s_waitcnt vmcnt(0)" ::: "memory"); }
    __builtin_amdgcn_s_barrier();

    // ---- PV + row-sum
    __builtin_amdgcn_s_setprio(1);
#pragma unroll
    for (int ks = 0; ks < 2; ++ks) {
      accL[0] = __builtin_amdgcn_mfma_f32_16x16x32_bf16(paf[0][ks], ONES, accL[0], 0, 0, 0);
      accL[1] = __builtin_amdgcn_mfma_f32_16x16x32_bf16(paf[1][ks], ONES, accL[1], 0, 0, 0);
#pragma unroll
      for (int dt = 0; dt < 4; ++dt) {
        bf16x8 vf = *(const bf16x8*)((ks == 0 ? vb0 : vb1) + cur * 8192 + dt * 2048);
        accO[0][dt] = __builtin_amdgcn_mfma_f32_16x16x32_bf16(paf[0][ks], vf, accO[0][dt], 0, 0, 0);
        accO[1][dt] = __builtin_amdgcn_mfma_f32_16x16x32_bf16(paf[1][ks], vf, accO[1][dt], 0, 0, 0);
      }
    }
    __builtin_amdgcn_s_setprio(0);

    // ---- gate K(t+1): counted; V(t+1) stays in flight into step t+1
    if (st) {
      asm volatile("s_waitcnt vmcnt(2)" ::: "memory");
      __builtin_amdgcn_s_barrier();
    }
  }

#pragma unroll
  for (int qh = 0; qh < 2; ++qh) {
    float inv[4];
#pragma unroll
    for (int r = 0; r < 4; ++r) inv[r] = 1.0f / accL[qh][r];
#pragma unroll
    for (int dt = 0; dt < 4; ++dt)
#pragma unroll
      for (int r = 0; r < 4; ++r) {
        const int s = q0 + wid * 32 + qh * 16 + rowg * 4 + r;
        out[((int64_t)b * SS + s) * HID + h * DH + dt * 16 + colL] = accO[qh][dt][r] * inv[r];
      }
  }
}

// ---------------- launch -----------------------------------------------------
extern "C" void kernel_launch(void* const* d_in, const int* in_sizes, int n_in,
                              void* d_out, int out_size, void* d_ws, size_t ws_size,
                              hipStream_t stream) {
  const float* x  = (const float*)d_in[0];
  const float* am = (const float*)d_in[1];
  const float* wq = (const float*)d_in[2];
  const float* bq = (const float*)d_in[3];
  const float* wk = (const float*)d_in[4];
  const float* bk = (const float*)d_in[5];
  const float* wv = (const float*)d_in[6];
  const float* bv = (const float*)d_in[7];
  float* out = (float*)d_out;
  char* ws = (char*)d_ws;

  ushort* xbf  = (ushort*)(ws);                    // 16 MB
  ushort* wbf  = (ushort*)(ws + 16777216);         // 6 MB
  ushort* qws  = (ushort*)(ws + 23068672);         // 16 MB [bh][s][64]
  ushort* kws  = (ushort*)(ws + 39845888);         // 16 MB [bh][s][64]
  ushort* vtws = (ushort*)(ws + 56623104);         // 16 MB [bh][64][s] (tau-permuted per 64)
  float*  mskL = (float*)(ws + 73400320);          // 32 KB mask*log2e

  hipLaunchKernelGGL(cvt_kernel, dim3(11272), dim3(256), 0, stream,
                     x, wq, wk, wv, am, xbf, wbf, mskL);
  hipLaunchKernelGGL(qkv_gemm, dim3(512), dim3(512), 0, stream,
                     xbf, wbf, bq, bk, bv, qws, kws, vtws);
  hipLaunchKernelGGL(attn_kernel, dim3(64, 16), dim3(256), 0, stream,
                     qws, kws, vtws, mskL, out);
}